// Round 1
// baseline (901.586 us; speedup 1.0000x reference)
//
#include <hip/hip_runtime.h>

typedef unsigned short u16;
typedef __attribute__((ext_vector_type(8))) short s16x8;
typedef __attribute__((ext_vector_type(8))) unsigned short u16x8;
typedef __attribute__((ext_vector_type(4))) float f32x4;

#define AS1 __attribute__((address_space(1)))
#define AS3 __attribute__((address_space(3)))

__device__ __forceinline__ float bf2f(u16 u) {
  union { unsigned u; float f; } x; x.u = ((unsigned)u) << 16; return x.f;
}
__device__ __forceinline__ u16 f2bf(float f) {
  union { float f; unsigned u; } x; x.f = f;
  unsigned r = x.u + 0x7fffu + ((x.u >> 16) & 1u);
  return (u16)(r >> 16);
}
__device__ __forceinline__ float celu_f(float x) {
  return x > 0.f ? x : 1.3f * expm1f(x * (1.0f / 1.3f));
}

// ---------------------------------------------------------------------------
// Transpose + fp32->bf16: WT[c*R + r] = bf16(W[r*C + c]).  grid(C/32, R/32), block(32,8)
// ---------------------------------------------------------------------------
__global__ __launch_bounds__(256) void transpose_bf16(
    const float* __restrict__ W, u16* __restrict__ WT, int R, int C)
{
  __shared__ float tile[32][33];
  const int bx = blockIdx.x, by = blockIdx.y;
  const int tx = threadIdx.x, ty = threadIdx.y;
#pragma unroll
  for (int i = ty; i < 32; i += 8)
    tile[i][tx] = W[(by * 32 + i) * C + bx * 32 + tx];
  __syncthreads();
#pragma unroll
  for (int i = ty; i < 32; i += 8)
    WT[(bx * 32 + i) * R + by * 32 + tx] = f2bf(tile[tx][i]);
}

// ---------------------------------------------------------------------------
// q / v1 branch, full fp32: out = groupnorm(celu(X@W + b)).
// grid: 64*8 blocks (row b, group grp), 128 threads = one group of channels.
// ---------------------------------------------------------------------------
__global__ __launch_bounds__(128) void branch_small(
    const float* __restrict__ X, const float* __restrict__ W,
    const float* __restrict__ bias, const float* __restrict__ gamma,
    const float* __restrict__ beta, float* __restrict__ out)
{
  const int b = blockIdx.x >> 3, grp = blockIdx.x & 7;
  const int t = threadIdx.x;
  __shared__ float xs[1024];
  __shared__ float r1[2], r2[2];
  for (int i = t; i < 1024; i += 128) xs[i] = X[b * 1024 + i];
  __syncthreads();
  const int col = grp * 128 + t;
  const float* wp = W + col;
  float a0 = 0.f, a1 = 0.f, a2 = 0.f, a3 = 0.f;
  for (int k = 0; k < 1024; k += 4) {
    a0 += xs[k]     * wp[(k)     * 1024];
    a1 += xs[k + 1] * wp[(k + 1) * 1024];
    a2 += xs[k + 2] * wp[(k + 2) * 1024];
    a3 += xs[k + 3] * wp[(k + 3) * 1024];
  }
  float x = (a0 + a1) + (a2 + a3) + bias[col];
  float c = celu_f(x);
  float s1 = c, s2 = c * c;
#pragma unroll
  for (int m = 1; m < 64; m <<= 1) { s1 += __shfl_xor(s1, m); s2 += __shfl_xor(s2, m); }
  const int w = t >> 6;
  if ((t & 63) == 0) { r1[w] = s1; r2[w] = s2; }
  __syncthreads();
  float t1 = r1[0] + r1[1], t2 = r2[0] + r2[1];
  float mean = t1 * 0.0078125f;
  float var  = t2 * 0.0078125f - mean * mean;
  float inv  = rsqrtf(var + 1e-5f);
  out[b * 1024 + col] = (c - mean) * inv * gamma[col] + beta[col];
}

// ---------------------------------------------------------------------------
// Big fused GEMM: C = groupnorm(celu(A @ W + b)) in bf16.
// A: 65536x1024 fp32 (reg-staged, converted to bf16, XOR-swizzled LDS).
// WT: 1024x1024 bf16, N-major (W^T), staged via global_load_lds w/ pre-swizzled src.
// Tile 128x128, BK=64, 4 waves (2x2), 16x16x32 bf16 MFMA, 4x4 frags/wave.
// BN=128 == group size -> GroupNorm fused in the epilogue.
// grid 4096 (XCD-bijective swizzled), block 256.
// ---------------------------------------------------------------------------
__global__ __launch_bounds__(256) void gemm_branch(
    const float* __restrict__ A, const u16* __restrict__ WT,
    const float* __restrict__ bias, const float* __restrict__ gamma,
    const float* __restrict__ beta, u16* __restrict__ Cout)
{
  __shared__ u16 Ash[128 * 64];
  __shared__ u16 Bsh[128 * 64];
  __shared__ float red[2][128][2];

  const int tid  = threadIdx.x;
  const int lane = tid & 63;
  const int w    = tid >> 6;
  const int wr   = w >> 1, wc = w & 1;
  const int lg   = lane >> 4, ln = lane & 15;

  // bijective XCD swizzle: consecutive mt panels stay on one XCD's L2
  const int bid = blockIdx.x;
  const int v   = (bid & 7) * 512 + (bid >> 3);
  const int mt  = v >> 3, nt = v & 7;

  const float* Abase = A + (long)mt * 128 * 1024;
  const int ar  = tid >> 3;   // 0..31 (row within sweep)
  const int akb = tid & 7;    // 0..7  (16B granule within row)

  f32x4 acc[4][4] = {};

  for (int kt = 0; kt < 16; ++kt) {
    const int k0 = kt * 64;
    // issue A global loads early (regs only, overlaps barrier wait)
    f32x4 av[8];
#pragma unroll
    for (int s = 0; s < 4; ++s) {
      const float* p = Abase + (s * 32 + ar) * 1024 + k0 + akb * 8;
      av[2 * s]     = *(const f32x4*)p;
      av[2 * s + 1] = *(const f32x4*)(p + 4);
    }
    __syncthreads();   // previous compute done reading LDS
    // B: global_load_lds, source pre-swizzled so linear LDS dest == swizzled layout
#pragma unroll
    for (int j = 0; j < 4; ++j) {
      int n  = j * 32 + w * 8 + (lane >> 3);
      int kb = (lane & 7) ^ (n & 7);
      const u16* src = WT + (nt * 128 + n) * 1024 + k0 + kb * 8;
      __builtin_amdgcn_global_load_lds((const AS1 void*)src,
                                       (AS3 void*)(&Bsh[j * 2048 + w * 512]), 16, 0, 0);
    }
    // A: convert fp32->bf16, ds_write_b128 at XOR-swizzled granule
#pragma unroll
    for (int s = 0; s < 4; ++s) {
      int row = s * 32 + ar;
      u16x8 t;
#pragma unroll
      for (int e = 0; e < 4; ++e) { t[e] = f2bf(av[2 * s][e]); t[4 + e] = f2bf(av[2 * s + 1][e]); }
      *(u16x8*)(&Ash[row * 64 + ((akb ^ (row & 7)) * 8)]) = t;
    }
    __syncthreads();   // drains vmcnt (B landed) + lgkm (A written)
#pragma unroll
    for (int ks = 0; ks < 2; ++ks) {
      const int kb = ks * 4 + lg;
      s16x8 af[4], bfv[4];
#pragma unroll
      for (int i = 0; i < 4; ++i) {
        int row = wr * 64 + i * 16 + ln;
        af[i] = *(const s16x8*)(&Ash[row * 64 + ((kb ^ (row & 7)) * 8)]);
        int n  = wc * 64 + i * 16 + ln;
        bfv[i] = *(const s16x8*)(&Bsh[n * 64 + ((kb ^ (n & 7)) * 8)]);
      }
#pragma unroll
      for (int i = 0; i < 4; ++i)
#pragma unroll
        for (int j = 0; j < 4; ++j)
          acc[i][j] = __builtin_amdgcn_mfma_f32_16x16x32_bf16(af[i], bfv[j], acc[i][j], 0, 0, 0);
    }
  }

  // ---- epilogue: bias + celu + groupnorm (group == this block's 128 cols) ----
  float bsv[4], gmv[4], btv[4];
#pragma unroll
  for (int j = 0; j < 4; ++j) {
    int col = nt * 128 + wc * 64 + j * 16 + ln;
    bsv[j] = bias[col]; gmv[j] = gamma[col]; btv[j] = beta[col];
  }
#pragma unroll
  for (int i = 0; i < 4; ++i)
#pragma unroll
    for (int j = 0; j < 4; ++j)
#pragma unroll
      for (int r = 0; r < 4; ++r)
        acc[i][j][r] = celu_f(acc[i][j][r] + bsv[j]);

  // per-row sum / sumsq over this wave's 64-col half, then cross-wc via LDS
#pragma unroll
  for (int i = 0; i < 4; ++i) {
#pragma unroll
    for (int r = 0; r < 4; ++r) {
      float s1 = acc[i][0][r] + acc[i][1][r] + acc[i][2][r] + acc[i][3][r];
      float s2 = acc[i][0][r] * acc[i][0][r] + acc[i][1][r] * acc[i][1][r] +
                 acc[i][2][r] * acc[i][2][r] + acc[i][3][r] * acc[i][3][r];
#pragma unroll
      for (int m = 1; m < 16; m <<= 1) { s1 += __shfl_xor(s1, m); s2 += __shfl_xor(s2, m); }
      if (ln == 0) {
        int rl = wr * 64 + i * 16 + 4 * lg + r;
        red[wc][rl][0] = s1; red[wc][rl][1] = s2;
      }
    }
  }
  __syncthreads();
#pragma unroll
  for (int i = 0; i < 4; ++i) {
#pragma unroll
    for (int r = 0; r < 4; ++r) {
      int rl = wr * 64 + i * 16 + 4 * lg + r;
      float t1 = red[0][rl][0] + red[1][rl][0];
      float t2 = red[0][rl][1] + red[1][rl][1];
      float mean = t1 * 0.0078125f;
      float var  = t2 * 0.0078125f - mean * mean;
      float inv  = rsqrtf(var + 1e-5f);
      long grow = (long)(mt * 128 + rl);
#pragma unroll
      for (int j = 0; j < 4; ++j) {
        float y = (acc[i][j][r] - mean) * inv * gmv[j] + btv[j];
        Cout[grow * 1024 + nt * 128 + wc * 64 + j * 16 + ln] = f2bf(y);
      }
    }
  }
}

// ---------------------------------------------------------------------------
// Stage 2: per (b,h) block: am = relu((q .* k) @ Wb + bb); pool; spatial
// softmax; channel sigmoid; pooled_v2; out = v1 * pooled_v2 * alpha_channel.
// grid 512 (b*8+h), block 256 (4 waves, each owns 256 m-rows).
// ---------------------------------------------------------------------------
__global__ __launch_bounds__(256) void stage2(
    const float* __restrict__ qb, const float* __restrict__ v1b,
    const u16* __restrict__ kbuf, const u16* __restrict__ v2buf,
    const u16* __restrict__ wbT, const float* __restrict__ bb,
    const float* __restrict__ Wl, const float* __restrict__ bl,
    const float* __restrict__ Wl2, const float* __restrict__ bl2,
    const float* __restrict__ mask, float* __restrict__ out)
{
  const int bh = blockIdx.x, b = bh >> 3, h = bh & 7;
  const int tid = threadIdx.x, lane = tid & 63, w = tid >> 6;
  const int lg = lane >> 4, ln = lane & 15;

  __shared__ float s_arr[1024];
  __shared__ float pool_l[4][64];
  __shared__ float poolf[64];
  __shared__ float ach[128];
  __shared__ float psum[128];
  __shared__ float rmsk[4], rmax[4], rsum[4];

  // q fragment values (fp32), per-lane slice of the 128-d head
  float qv[4][8];
#pragma unroll
  for (int ks = 0; ks < 4; ++ks)
#pragma unroll
    for (int e = 0; e < 8; ++e)
      qv[ks][e] = qb[b * 1024 + h * 128 + ks * 32 + lg * 8 + e];

  // Wb^T fragments resident in registers (16 KB total, L2-hot)
  s16x8 bfr[4][4];
#pragma unroll
  for (int nj = 0; nj < 4; ++nj)
#pragma unroll
    for (int ks = 0; ks < 4; ++ks)
      bfr[nj][ks] = *(const s16x8*)(&wbT[(nj * 16 + ln) * 128 + ks * 32 + lg * 8]);

  float wlv[4], bbv[4];
#pragma unroll
  for (int nj = 0; nj < 4; ++nj) { wlv[nj] = Wl[nj * 16 + ln]; bbv[nj] = bb[nj * 16 + ln]; }

  float mpart = 0.f;
  for (int m = tid; m < 1024; m += 256) mpart += mask[b * 1024 + m];

  float poolacc[4] = {0.f, 0.f, 0.f, 0.f};

  for (int c = 0; c < 16; ++c) {
    const int m0 = w * 256 + c * 16;
    f32x4 amacc[4] = {};
#pragma unroll
    for (int ks = 0; ks < 4; ++ks) {
      const u16* kp = kbuf + (long)(b * 1024 + m0 + ln) * 1024 + h * 128 + ks * 32 + lg * 8;
      u16x8 kw = *(const u16x8*)kp;
      s16x8 af;
#pragma unroll
      for (int e = 0; e < 8; ++e) af[e] = (short)f2bf(bf2f(kw[e]) * qv[ks][e]);
#pragma unroll
      for (int nj = 0; nj < 4; ++nj)
        amacc[nj] = __builtin_amdgcn_mfma_f32_16x16x32_bf16(af, bfr[nj][ks], amacc[nj], 0, 0, 0);
    }
    float mrow[4];
#pragma unroll
    for (int r = 0; r < 4; ++r) mrow[r] = mask[b * 1024 + m0 + lg * 4 + r];
    float sp[4] = {0.f, 0.f, 0.f, 0.f};
#pragma unroll
    for (int nj = 0; nj < 4; ++nj)
#pragma unroll
      for (int r = 0; r < 4; ++r) {
        float a = fmaxf(amacc[nj][r] + bbv[nj], 0.f);
        poolacc[nj] += a * mrow[r];
        sp[r] += a * wlv[nj];
      }
#pragma unroll
    for (int m = 1; m < 16; m <<= 1)
#pragma unroll
      for (int r = 0; r < 4; ++r) sp[r] += __shfl_xor(sp[r], m);
    if (ln == 0) {
#pragma unroll
      for (int r = 0; r < 4; ++r) s_arr[m0 + lg * 4 + r] = sp[r] + bl[0];
    }
  }
#pragma unroll
  for (int m = 16; m < 64; m <<= 1)
#pragma unroll
    for (int nj = 0; nj < 4; ++nj) poolacc[nj] += __shfl_xor(poolacc[nj], m);
  if (lg == 0) {
#pragma unroll
    for (int nj = 0; nj < 4; ++nj) pool_l[w][nj * 16 + ln] = poolacc[nj];
  }
#pragma unroll
  for (int m = 1; m < 64; m <<= 1) mpart += __shfl_xor(mpart, m);
  if (lane == 0) rmsk[w] = mpart;
  __syncthreads();   // B1
  const float msum = rmsk[0] + rmsk[1] + rmsk[2] + rmsk[3];
  if (tid < 64) poolf[tid] = pool_l[0][tid] + pool_l[1][tid] + pool_l[2][tid] + pool_l[3][tid];
  float lmax = -3.0e38f;
  for (int m = tid; m < 1024; m += 256) {
    float sv = (mask[b * 1024 + m] == 0.f) ? -1.0e9f : s_arr[m];
    s_arr[m] = sv;
    lmax = fmaxf(lmax, sv);
  }
#pragma unroll
  for (int m = 1; m < 64; m <<= 1) lmax = fmaxf(lmax, __shfl_xor(lmax, m));
  if (lane == 0) rmax[w] = lmax;
  __syncthreads();   // B2
  const float gmax = fmaxf(fmaxf(rmax[0], rmax[1]), fmaxf(rmax[2], rmax[3]));
  float lsum = 0.f;
  for (int m = tid; m < 1024; m += 256) {
    float e = expf(s_arr[m] - gmax);
    s_arr[m] = e;
    lsum += e;
  }
#pragma unroll
  for (int m = 1; m < 64; m <<= 1) lsum += __shfl_xor(lsum, m);
  if (lane == 0) rsum[w] = lsum;
  if (tid < 128) {
    float a = 0.f;
    for (int cc = 0; cc < 64; ++cc) a += poolf[cc] * Wl2[cc * 128 + tid];
    a = a / msum + bl2[tid];
    ach[tid] = 1.f / (1.f + expf(-a));
  }
  __syncthreads();   // B3
  const float gsum = rsum[0] + rsum[1] + rsum[2] + rsum[3];
  const int d = tid & 127, half = tid >> 7;
  const u16* vp = v2buf + (long)(b * 1024 + half * 512) * 1024 + h * 128 + d;
  float pacc = 0.f;
#pragma unroll 4
  for (int m = 0; m < 512; ++m)
    pacc += s_arr[half * 512 + m] * bf2f(vp[(long)m * 1024]);
  pacc *= 1.f / gsum;
  if (half) psum[d] = pacc;
  __syncthreads();   // B4
  if (tid < 128) {
    float pooled = pacc + psum[tid];
    out[b * 1024 + h * 128 + tid] = v1b[b * 1024 + h * 128 + tid] * pooled * ach[tid];
  }
}

// ---------------------------------------------------------------------------
extern "C" void kernel_launch(void* const* d_in, const int* in_sizes, int n_in,
                              void* d_out, int out_size, void* d_ws, size_t ws_size,
                              hipStream_t stream)
{
  (void)in_sizes; (void)n_in; (void)out_size; (void)ws_size;
  const float* query  = (const float*)d_in[0];
  const float* key    = (const float*)d_in[1];
  const float* mask   = (const float*)d_in[2];
  const float* value1 = (const float*)d_in[3];
  const float* value2 = (const float*)d_in[4];
  const float* Wq  = (const float*)d_in[5];
  const float* bq  = (const float*)d_in[6];
  const float* gq  = (const float*)d_in[7];
  const float* gbq = (const float*)d_in[8];
  const float* Wk  = (const float*)d_in[9];
  const float* bk  = (const float*)d_in[10];
  const float* gk  = (const float*)d_in[11];
  const float* gbk = (const float*)d_in[12];
  const float* Wv1  = (const float*)d_in[13];
  const float* bv1  = (const float*)d_in[14];
  const float* gv1  = (const float*)d_in[15];
  const float* gbv1 = (const float*)d_in[16];
  const float* Wv2  = (const float*)d_in[17];
  const float* bv2  = (const float*)d_in[18];
  const float* gv2  = (const float*)d_in[19];
  const float* gbv2 = (const float*)d_in[20];
  const float* Wb  = (const float*)d_in[21];
  const float* bb  = (const float*)d_in[22];
  const float* Wl  = (const float*)d_in[23];
  const float* bl  = (const float*)d_in[24];
  const float* Wl2 = (const float*)d_in[25];
  const float* bl2 = (const float*)d_in[26];
  float* out = (float*)d_out;

  char* ws = (char*)d_ws;
  u16*   k_out  = (u16*)(ws);
  u16*   v2_out = (u16*)(ws + 134217728L);
  u16*   WkT    = (u16*)(ws + 268435456L);
  u16*   Wv2T   = (u16*)(ws + 268435456L + 2097152L);
  u16*   WbT    = (u16*)(ws + 268435456L + 2L * 2097152L);
  float* qbuf   = (float*)(ws + 268435456L + 2L * 2097152L + 32768L);
  float* v1buf  = (float*)(ws + 268435456L + 2L * 2097152L + 32768L + 262144L);

  dim3 tb(32, 8);
  transpose_bf16<<<dim3(32, 32), tb, 0, stream>>>(Wk,  WkT,  1024, 1024);
  transpose_bf16<<<dim3(32, 32), tb, 0, stream>>>(Wv2, Wv2T, 1024, 1024);
  transpose_bf16<<<dim3(2, 4),   tb, 0, stream>>>(Wb,  WbT,  128,  64);

  branch_small<<<512, 128, 0, stream>>>(query,  Wq,  bq,  gq,  gbq,  qbuf);
  branch_small<<<512, 128, 0, stream>>>(value1, Wv1, bv1, gv1, gbv1, v1buf);

  gemm_branch<<<4096, 256, 0, stream>>>(key,    WkT,  bk,  gk,  gbk,  k_out);
  gemm_branch<<<4096, 256, 0, stream>>>(value2, Wv2T, bv2, gv2, gbv2, v2_out);

  stage2<<<512, 256, 0, stream>>>(qbuf, v1buf, k_out, v2_out, WbT,
                                  bb, Wl, bl, Wl2, bl2, mask, out);
}